// Round 1
// baseline (254.402 us; speedup 1.0000x reference)
//
#include <hip/hip_runtime.h>
#include <stdint.h>

// MultiHeadAttention fused pipeline for MI355X (gfx950).
// B=2, S=2048, D=1024, H=16, dk=64. fp32 in/out, bf16 MFMA compute.

#define AS1 __attribute__((address_space(1)))
#define AS3 __attribute__((address_space(3)))

typedef unsigned short u16;
typedef short s16x8 __attribute__((ext_vector_type(8)));   // 8 bf16 (4 VGPRs) MFMA frag
typedef float f32x4 __attribute__((ext_vector_type(4)));   // MFMA accumulator
typedef u16   u16x4 __attribute__((ext_vector_type(4)));

#if defined(__has_builtin)
#if __has_builtin(__builtin_amdgcn_exp2f)
#define EXP2F(x) __builtin_amdgcn_exp2f(x)
#else
#define EXP2F(x) exp2f(x)
#endif
#else
#define EXP2F(x) exp2f(x)
#endif

__device__ __forceinline__ u16 f2b(float f) {  // fp32 -> bf16 RNE
  union { float f; uint32_t u; } v;
  v.f = f;
  uint32_t r = (v.u + 0x7fffu + ((v.u >> 16) & 1u)) >> 16;
  return (u16)r;
}

__device__ __forceinline__ f32x4 mfma16(s16x8 a, s16x8 b, f32x4 c) {
  return __builtin_amdgcn_mfma_f32_16x16x32_bf16(a, b, c, 0, 0, 0);
}

__device__ __forceinline__ s16x8 ld_g16(const u16* p) {
  return *reinterpret_cast<const s16x8*>(p);
}

// async global->LDS, 16B per lane. LDS dest must be WAVE-UNIFORM base; HW adds lane*16.
__device__ __forceinline__ void stage16(const u16* g, u16* lds_base) {
  __builtin_amdgcn_global_load_lds((const AS1 unsigned int*)g,
                                   (AS3 unsigned int*)lds_base, 16, 0, 0);
}

// ---------------------------------------------------------------- fp32 -> bf16
__global__ __launch_bounds__(256) void cvt_f32_bf16(const float* __restrict__ src,
                                                    u16* __restrict__ dst, int n4) {
  int i = blockIdx.x * 256 + threadIdx.x;
  if (i >= n4) return;
  float4 f = reinterpret_cast<const float4*>(src)[i];
  union { u16 u[4]; uint64_t q; } o;
  o.u[0] = f2b(f.x); o.u[1] = f2b(f.y); o.u[2] = f2b(f.z); o.u[3] = f2b(f.w);
  reinterpret_cast<uint64_t*>(dst)[i] = o.q;
}

// ---------------------------------------------------------------- GEMM  C = A @ W^T + bias
// A: [4096][1024] bf16 row-major. W: [1024][1024] bf16 row-major (rows = out features == B^T).
// MODE 0: out bf16, head-split layout [B,H,S,dk]; blockIdx.z selects {q,k,v}.
// MODE 1: out fp32 [4096][1024] (final projection).
template <int MODE>
__global__ __launch_bounds__(256) void gemm_bt(const u16* __restrict__ Abase,
                                               const u16* __restrict__ Wbase,
                                               const float* __restrict__ bias0,
                                               const float* __restrict__ bias1,
                                               const float* __restrict__ bias2,
                                               u16* __restrict__ outb,
                                               float* __restrict__ outf) {
  __shared__ u16 As[128 * 32];
  __shared__ u16 Bs[128 * 32];
  const int tid = threadIdx.x;
  const int lane = tid & 63;
  const int w = tid >> 6;
  const int wr = w >> 1, wc = w & 1;       // 2x2 wave grid, each wave 64x64
  const int m0 = blockIdx.y * 128;
  const int n0 = blockIdx.x * 128;
  const int z = (MODE == 0) ? blockIdx.z : 0;

  const u16* A = Abase + (size_t)z * (4096u * 1024u);
  const u16* W = Wbase + (size_t)z * (1024u * 1024u);
  const float* bias = (MODE == 0) ? (z == 0 ? bias0 : (z == 1 ? bias1 : bias2)) : bias0;
  u16* ob = (MODE == 0) ? (outb + (size_t)z * (4096u * 1024u)) : nullptr;

  const int l15 = lane & 15, l4 = lane >> 4;
  const int srow = lane >> 2;              // staging: 16 rows x 4 chunks of 16B per wave-call
  const int scol = (lane & 3) * 8;
  const int i0 = w * 2, i1 = w * 2 + 1;    // this wave's 1KB chunks (of 8)

  f32x4 acc[4][4];
#pragma unroll
  for (int i = 0; i < 4; ++i)
#pragma unroll
    for (int j = 0; j < 4; ++j) acc[i][j] = {0.f, 0.f, 0.f, 0.f};

  for (int kt = 0; kt < 1024; kt += 32) {
    __syncthreads();
    stage16(A + (size_t)(m0 + i0 * 16 + srow) * 1024 + kt + scol, &As[i0 * 512]);
    stage16(A + (size_t)(m0 + i1 * 16 + srow) * 1024 + kt + scol, &As[i1 * 512]);
    stage16(W + (size_t)(n0 + i0 * 16 + srow) * 1024 + kt + scol, &Bs[i0 * 512]);
    stage16(W + (size_t)(n0 + i1 * 16 + srow) * 1024 + kt + scol, &Bs[i1 * 512]);
    __syncthreads();

    s16x8 af[4], bf[4];
#pragma unroll
    for (int mi = 0; mi < 4; ++mi)
      af[mi] = *(const s16x8*)&As[(wr * 64 + mi * 16 + l15) * 32 + l4 * 8];
#pragma unroll
    for (int ni = 0; ni < 4; ++ni)
      bf[ni] = *(const s16x8*)&Bs[(wc * 64 + ni * 16 + l15) * 32 + l4 * 8];
#pragma unroll
    for (int mi = 0; mi < 4; ++mi)
#pragma unroll
      for (int ni = 0; ni < 4; ++ni)
        acc[mi][ni] = mfma16(af[mi], bf[ni], acc[mi][ni]);
  }

#pragma unroll
  for (int ni = 0; ni < 4; ++ni) {
    const int col = n0 + wc * 64 + ni * 16 + l15;
    const float bv = bias[col];
#pragma unroll
    for (int mi = 0; mi < 4; ++mi) {
      const int row0 = m0 + wr * 64 + mi * 16 + l4 * 4;
#pragma unroll
      for (int r = 0; r < 4; ++r) {
        const float val = acc[mi][ni][r] + bv;
        const int row = row0 + r;
        if (MODE == 0) {
          const int b = row >> 11, s = row & 2047;
          const int h = col >> 6, d = col & 63;
          ob[((size_t)(b * 16 + h) * 2048 + s) * 64 + d] = f2b(val);
        } else {
          outf[(size_t)row * 1024 + col] = val;
        }
      }
    }
  }
}

// ---------------------------------------------------------------- v [bh][s][d] -> vT [bh][d][s]
__global__ __launch_bounds__(256) void transpose64(const u16* __restrict__ v,
                                                   u16* __restrict__ vt) {
  __shared__ u16 t[64][65];
  const int bh = blockIdx.y;
  const int s0 = blockIdx.x * 64;
  const u16* vb = v + (size_t)bh * (2048 * 64);
  u16* vtb = vt + (size_t)bh * (64 * 2048);
  const int tid = threadIdx.x;
#pragma unroll
  for (int i = 0; i < 4; ++i) {
    int c = tid + 256 * i;
    int row = c >> 4, c4 = (c & 15) * 4;
    u16x4 x = *(const u16x4*)&vb[(size_t)(s0 + row) * 64 + c4];
    t[row][c4 + 0] = x.x; t[row][c4 + 1] = x.y; t[row][c4 + 2] = x.z; t[row][c4 + 3] = x.w;
  }
  __syncthreads();
#pragma unroll
  for (int i = 0; i < 4; ++i) {
    int c = tid + 256 * i;
    int d = c >> 4, s4 = (c & 15) * 4;
    u16x4 y;
    y.x = t[s4 + 0][d]; y.y = t[s4 + 1][d]; y.z = t[s4 + 2][d]; y.w = t[s4 + 3][d];
    *(u16x4*)&vtb[(size_t)d * 2048 + s0 + s4] = y;
  }
}

// ---------------------------------------------------------------- flash attention
// q,k: [B,H,S,dk] bf16.  vT: [B,H,dk,S] bf16.  out: bf16 [B*S][D] (col = h*64+d).
// Block: 4 waves x 32 q-rows = 128 q-rows per (b,h). KT=64 keys/iter, online softmax.
__global__ __launch_bounds__(256) void fattn(const u16* __restrict__ qp,
                                             const u16* __restrict__ kp,
                                             const u16* __restrict__ vt,
                                             u16* __restrict__ ao) {
  __shared__ u16 P[4][32 * 72];            // per-wave P tile, padded stride 72
  const int lane = threadIdx.x & 63;
  const int w = threadIdx.x >> 6;
  const int bh = blockIdx.y;
  const int b = bh >> 4, h = bh & 15;
  const int q0 = blockIdx.x * 128 + w * 32;  // this wave's first q row
  const u16* qb = qp + (size_t)bh * (2048 * 64);
  const u16* kb = kp + (size_t)bh * (2048 * 64);
  const u16* vb = vt + (size_t)bh * (64 * 2048);
  u16* Pw = &P[w][0];
  const int l15 = lane & 15, l4 = lane >> 4;
  const float KSC = 0.18033688011112042f;  // log2(e) / sqrt(dk)

  s16x8 qa[2][2];
#pragma unroll
  for (int mi = 0; mi < 2; ++mi)
#pragma unroll
    for (int ks = 0; ks < 2; ++ks)
      qa[mi][ks] = ld_g16(qb + (size_t)(q0 + mi * 16 + l15) * 64 + ks * 32 + l4 * 8);

  f32x4 o[2][4];
  float mrun[2][4], lrun[2][4];
#pragma unroll
  for (int mi = 0; mi < 2; ++mi) {
#pragma unroll
    for (int ni = 0; ni < 4; ++ni) o[mi][ni] = {0.f, 0.f, 0.f, 0.f};
#pragma unroll
    for (int r = 0; r < 4; ++r) { mrun[mi][r] = -1e30f; lrun[mi][r] = 0.f; }
  }

  for (int k0 = 0; k0 < 2048; k0 += 64) {
    // ---- QK^T : scores [32 q][64 keys]
    f32x4 sc[2][4];
#pragma unroll
    for (int mi = 0; mi < 2; ++mi)
#pragma unroll
      for (int nk = 0; nk < 4; ++nk) sc[mi][nk] = {0.f, 0.f, 0.f, 0.f};
#pragma unroll
    for (int ks = 0; ks < 2; ++ks) {
      s16x8 kf[4];
#pragma unroll
      for (int nk = 0; nk < 4; ++nk)
        kf[nk] = ld_g16(kb + (size_t)(k0 + nk * 16 + l15) * 64 + ks * 32 + l4 * 8);
#pragma unroll
      for (int mi = 0; mi < 2; ++mi)
#pragma unroll
        for (int nk = 0; nk < 4; ++nk)
          sc[mi][nk] = mfma16(qa[mi][ks], kf[nk], sc[mi][nk]);
    }
    // ---- per-row max over 64 keys (4 frags + 16-lane butterfly)
    float mx[2][4];
#pragma unroll
    for (int mi = 0; mi < 2; ++mi)
#pragma unroll
      for (int r = 0; r < 4; ++r)
        mx[mi][r] = fmaxf(fmaxf(sc[mi][0][r], sc[mi][1][r]),
                          fmaxf(sc[mi][2][r], sc[mi][3][r]));
#pragma unroll
    for (int msk = 1; msk < 16; msk <<= 1)
#pragma unroll
      for (int mi = 0; mi < 2; ++mi)
#pragma unroll
        for (int r = 0; r < 4; ++r)
          mx[mi][r] = fmaxf(mx[mi][r], __shfl_xor(mx[mi][r], msk));
    // ---- online-softmax rescale
    float alpha[2][4];
#pragma unroll
    for (int mi = 0; mi < 2; ++mi)
#pragma unroll
      for (int r = 0; r < 4; ++r) {
        float mn = fmaxf(mrun[mi][r], mx[mi][r] * KSC);
        alpha[mi][r] = EXP2F(mrun[mi][r] - mn);
        mrun[mi][r] = mn;
        lrun[mi][r] *= alpha[mi][r];
      }
#pragma unroll
    for (int mi = 0; mi < 2; ++mi)
#pragma unroll
      for (int ni = 0; ni < 4; ++ni)
#pragma unroll
        for (int r = 0; r < 4; ++r) o[mi][ni][r] *= alpha[mi][r];
    // ---- P = exp2(s*KSC - m), row-sum, write to LDS (bf16)
    float ps[2][4];
#pragma unroll
    for (int mi = 0; mi < 2; ++mi)
#pragma unroll
      for (int r = 0; r < 4; ++r) ps[mi][r] = 0.f;
#pragma unroll
    for (int mi = 0; mi < 2; ++mi)
#pragma unroll
      for (int nk = 0; nk < 4; ++nk)
#pragma unroll
        for (int r = 0; r < 4; ++r) {
          float p = EXP2F(sc[mi][nk][r] * KSC - mrun[mi][r]);
          ps[mi][r] += p;
          Pw[(mi * 16 + l4 * 4 + r) * 72 + nk * 16 + l15] = f2b(p);
        }
#pragma unroll
    for (int msk = 1; msk < 16; msk <<= 1)
#pragma unroll
      for (int mi = 0; mi < 2; ++mi)
#pragma unroll
        for (int r = 0; r < 4; ++r)
          ps[mi][r] += __shfl_xor(ps[mi][r], msk);
#pragma unroll
    for (int mi = 0; mi < 2; ++mi)
#pragma unroll
      for (int r = 0; r < 4; ++r) lrun[mi][r] += ps[mi][r];

    asm volatile("" ::: "memory");  // order LDS P writes before reads (same wave, DS in-order)
    // ---- PV : o += P @ v   (B-frags straight from global vT, L2-resident)
#pragma unroll
    for (int ks = 0; ks < 2; ++ks) {
      s16x8 pa[2];
      pa[0] = *(const s16x8*)&Pw[(0 * 16 + l15) * 72 + ks * 32 + l4 * 8];
      pa[1] = *(const s16x8*)&Pw[(1 * 16 + l15) * 72 + ks * 32 + l4 * 8];
#pragma unroll
      for (int ni = 0; ni < 4; ++ni) {
        s16x8 vf = ld_g16(vb + (size_t)(ni * 16 + l15) * 2048 + k0 + ks * 32 + l4 * 8);
        o[0][ni] = mfma16(pa[0], vf, o[0][ni]);
        o[1][ni] = mfma16(pa[1], vf, o[1][ni]);
      }
    }
    asm volatile("" ::: "memory");  // keep next-iter P writes after these reads
  }

  // ---- epilogue: normalize and store bf16 [B*S][1024]
#pragma unroll
  for (int mi = 0; mi < 2; ++mi)
#pragma unroll
    for (int ni = 0; ni < 4; ++ni)
#pragma unroll
      for (int r = 0; r < 4; ++r) {
        float val = o[mi][ni][r] / lrun[mi][r];
        int row = b * 2048 + q0 + mi * 16 + l4 * 4 + r;
        int col = h * 64 + ni * 16 + l15;
        ao[(size_t)row * 1024 + col] = f2b(val);
      }
}

// ---------------------------------------------------------------- host
extern "C" void kernel_launch(void* const* d_in, const int* in_sizes, int n_in,
                              void* d_out, int out_size, void* d_ws, size_t ws_size,
                              hipStream_t stream) {
  const float* Q  = (const float*)d_in[0];
  const float* K  = (const float*)d_in[1];
  const float* V  = (const float*)d_in[2];
  const float* Wq = (const float*)d_in[3];
  const float* bq = (const float*)d_in[4];
  const float* Wk = (const float*)d_in[5];
  const float* bk = (const float*)d_in[6];
  const float* Wv = (const float*)d_in[7];
  const float* bv = (const float*)d_in[8];
  const float* Wo = (const float*)d_in[9];
  const float* bo = (const float*)d_in[10];
  float* out = (float*)d_out;

  const size_t NI = (size_t)4096 * 1024;  // elements per [B*S, D] tensor
  const size_t NW = (size_t)1024 * 1024;  // elements per weight
  u16* XB  = (u16*)d_ws;          // Qb,Kb,Vb bf16 (3*NI)
  u16* WB  = XB + 3 * NI;         // Wq,Wk,Wv,Wo bf16 (4*NW)
  u16* QKV = WB + 4 * NW;         // q,k,v [B,H,S,dk] bf16 (3*NI)
  u16* VT  = QKV + 3 * NI;        // vT [B,H,dk,S] bf16 (NI)
  u16* AO  = VT + NI;             // attention output bf16 [B*S][D] (NI)

  // fp32 -> bf16
  cvt_f32_bf16<<<dim3((int)(NI / 4 / 256)), 256, 0, stream>>>(Q, XB, (int)(NI / 4));
  cvt_f32_bf16<<<dim3((int)(NI / 4 / 256)), 256, 0, stream>>>(K, XB + NI, (int)(NI / 4));
  cvt_f32_bf16<<<dim3((int)(NI / 4 / 256)), 256, 0, stream>>>(V, XB + 2 * NI, (int)(NI / 4));
  cvt_f32_bf16<<<dim3((int)(NW / 4 / 256)), 256, 0, stream>>>(Wq, WB, (int)(NW / 4));
  cvt_f32_bf16<<<dim3((int)(NW / 4 / 256)), 256, 0, stream>>>(Wk, WB + NW, (int)(NW / 4));
  cvt_f32_bf16<<<dim3((int)(NW / 4 / 256)), 256, 0, stream>>>(Wv, WB + 2 * NW, (int)(NW / 4));
  cvt_f32_bf16<<<dim3((int)(NW / 4 / 256)), 256, 0, stream>>>(Wo, WB + 3 * NW, (int)(NW / 4));

  // q,k,v projections (z = 0,1,2)
  gemm_bt<0><<<dim3(8, 32, 3), 256, 0, stream>>>(XB, WB, bq, bk, bv, QKV, nullptr);
  // v -> vT
  transpose64<<<dim3(32, 32), 256, 0, stream>>>(QKV + 2 * NI, VT);
  // attention
  fattn<<<dim3(16, 32), 256, 0, stream>>>(QKV, QKV + NI, VT, AO);
  // output projection
  gemm_bt<1><<<dim3(8, 32, 1), 256, 0, stream>>>(AO, WB + 3 * NW, bo, nullptr, nullptr,
                                                 nullptr, out);
}

// Round 2
// 235.478 us; speedup vs baseline: 1.0804x; 1.0804x over previous
//
#include <hip/hip_runtime.h>
#include <stdint.h>

// MultiHeadAttention fused pipeline for MI355X (gfx950).
// B=2, S=2048, D=1024, H=16, dk=64. fp32 in/out, bf16 MFMA compute.

#define AS1 __attribute__((address_space(1)))
#define AS3 __attribute__((address_space(3)))

typedef unsigned short u16;
typedef short s16x8 __attribute__((ext_vector_type(8)));   // 8 bf16 (4 VGPRs) MFMA frag
typedef float f32x4 __attribute__((ext_vector_type(4)));   // MFMA accumulator
typedef u16   u16x4 __attribute__((ext_vector_type(4)));

#if defined(__has_builtin)
#if __has_builtin(__builtin_amdgcn_exp2f)
#define EXP2F(x) __builtin_amdgcn_exp2f(x)
#else
#define EXP2F(x) exp2f(x)
#endif
#else
#define EXP2F(x) exp2f(x)
#endif

__device__ __forceinline__ u16 f2b(float f) {  // fp32 -> bf16 RNE
  union { float f; uint32_t u; } v;
  v.f = f;
  uint32_t r = (v.u + 0x7fffu + ((v.u >> 16) & 1u)) >> 16;
  return (u16)r;
}

__device__ __forceinline__ f32x4 mfma16(s16x8 a, s16x8 b, f32x4 c) {
  return __builtin_amdgcn_mfma_f32_16x16x32_bf16(a, b, c, 0, 0, 0);
}

__device__ __forceinline__ s16x8 ld_g16(const u16* p) {
  return *reinterpret_cast<const s16x8*>(p);
}

// async global->LDS, 16B per lane. LDS dest must be WAVE-UNIFORM base; HW adds lane*16.
__device__ __forceinline__ void stage16(const u16* g, u16* lds_base) {
  __builtin_amdgcn_global_load_lds((const AS1 unsigned int*)g,
                                   (AS3 unsigned int*)lds_base, 16, 0, 0);
}

// ---------------------------------------------------------------- fp32 -> bf16
__global__ __launch_bounds__(256) void cvt_f32_bf16(const float* __restrict__ src,
                                                    u16* __restrict__ dst, int n4) {
  int i = blockIdx.x * 256 + threadIdx.x;
  if (i >= n4) return;
  float4 f = reinterpret_cast<const float4*>(src)[i];
  union { u16 u[4]; uint64_t q; } o;
  o.u[0] = f2b(f.x); o.u[1] = f2b(f.y); o.u[2] = f2b(f.z); o.u[3] = f2b(f.w);
  reinterpret_cast<uint64_t*>(dst)[i] = o.q;
}

// ---------------------------------------------------------------- GEMM  C = A @ W^T + bias
template <int MODE>
__global__ __launch_bounds__(256) void gemm_bt(const u16* __restrict__ Abase,
                                               const u16* __restrict__ Wbase,
                                               const float* __restrict__ bias0,
                                               const float* __restrict__ bias1,
                                               const float* __restrict__ bias2,
                                               u16* __restrict__ outb,
                                               float* __restrict__ outf) {
  __shared__ u16 As[128 * 32];
  __shared__ u16 Bs[128 * 32];
  const int tid = threadIdx.x;
  const int lane = tid & 63;
  const int w = tid >> 6;
  const int wr = w >> 1, wc = w & 1;       // 2x2 wave grid, each wave 64x64
  const int m0 = blockIdx.y * 128;
  const int n0 = blockIdx.x * 128;
  const int z = (MODE == 0) ? blockIdx.z : 0;

  const u16* A = Abase + (size_t)z * (4096u * 1024u);
  const u16* W = Wbase + (size_t)z * (1024u * 1024u);
  const float* bias = (MODE == 0) ? (z == 0 ? bias0 : (z == 1 ? bias1 : bias2)) : bias0;
  u16* ob = (MODE == 0) ? (outb + (size_t)z * (4096u * 1024u)) : nullptr;

  const int l15 = lane & 15, l4 = lane >> 4;
  const int srow = lane >> 2;
  const int scol = (lane & 3) * 8;
  const int i0 = w * 2, i1 = w * 2 + 1;

  f32x4 acc[4][4];
#pragma unroll
  for (int i = 0; i < 4; ++i)
#pragma unroll
    for (int j = 0; j < 4; ++j) acc[i][j] = {0.f, 0.f, 0.f, 0.f};

  for (int kt = 0; kt < 1024; kt += 32) {
    __syncthreads();
    stage16(A + (size_t)(m0 + i0 * 16 + srow) * 1024 + kt + scol, &As[i0 * 512]);
    stage16(A + (size_t)(m0 + i1 * 16 + srow) * 1024 + kt + scol, &As[i1 * 512]);
    stage16(W + (size_t)(n0 + i0 * 16 + srow) * 1024 + kt + scol, &Bs[i0 * 512]);
    stage16(W + (size_t)(n0 + i1 * 16 + srow) * 1024 + kt + scol, &Bs[i1 * 512]);
    __syncthreads();

    s16x8 af[4], bf[4];
#pragma unroll
    for (int mi = 0; mi < 4; ++mi)
      af[mi] = *(const s16x8*)&As[(wr * 64 + mi * 16 + l15) * 32 + l4 * 8];
#pragma unroll
    for (int ni = 0; ni < 4; ++ni)
      bf[ni] = *(const s16x8*)&Bs[(wc * 64 + ni * 16 + l15) * 32 + l4 * 8];
#pragma unroll
    for (int mi = 0; mi < 4; ++mi)
#pragma unroll
      for (int ni = 0; ni < 4; ++ni)
        acc[mi][ni] = mfma16(af[mi], bf[ni], acc[mi][ni]);
  }

#pragma unroll
  for (int ni = 0; ni < 4; ++ni) {
    const int col = n0 + wc * 64 + ni * 16 + l15;
    const float bv = bias[col];
#pragma unroll
    for (int mi = 0; mi < 4; ++mi) {
      const int row0 = m0 + wr * 64 + mi * 16 + l4 * 4;
#pragma unroll
      for (int r = 0; r < 4; ++r) {
        const float val = acc[mi][ni][r] + bv;
        const int row = row0 + r;
        if (MODE == 0) {
          const int b = row >> 11, s = row & 2047;
          const int h = col >> 6, d = col & 63;
          ob[((size_t)(b * 16 + h) * 2048 + s) * 64 + d] = f2b(val);
        } else {
          outf[(size_t)row * 1024 + col] = val;
        }
      }
    }
  }
}

// ---------------------------------------------------------------- v [bh][s][d] -> vT [bh][d][s]
__global__ __launch_bounds__(256) void transpose64(const u16* __restrict__ v,
                                                   u16* __restrict__ vt) {
  __shared__ u16 t[64][65];
  const int bh = blockIdx.y;
  const int s0 = blockIdx.x * 64;
  const u16* vb = v + (size_t)bh * (2048 * 64);
  u16* vtb = vt + (size_t)bh * (64 * 2048);
  const int tid = threadIdx.x;
#pragma unroll
  for (int i = 0; i < 4; ++i) {
    int c = tid + 256 * i;
    int row = c >> 4, c4 = (c & 15) * 4;
    u16x4 x = *(const u16x4*)&vb[(size_t)(s0 + row) * 64 + c4];
    t[row][c4 + 0] = x.x; t[row][c4 + 1] = x.y; t[row][c4 + 2] = x.z; t[row][c4 + 3] = x.w;
  }
  __syncthreads();
#pragma unroll
  for (int i = 0; i < 4; ++i) {
    int c = tid + 256 * i;
    int d = c >> 4, s4 = (c & 15) * 4;
    u16x4 y;
    y.x = t[s4 + 0][d]; y.y = t[s4 + 1][d]; y.z = t[s4 + 2][d]; y.w = t[s4 + 3][d];
    *(u16x4*)&vtb[(size_t)d * 2048 + s0 + s4] = y;
  }
}

// ---------------------------------------------------------------- flash attention
// Swapped QK^T: sc = mfma(K, Q) -> D[key][q], lane (l15) owns one q column.
// Block: 4 waves = 2 q-tiles(32) x 2 k-halves(1024). Merge halves via LDS.
// q,k: [B,H,S,dk] bf16. vT: [B,H,dk,S] bf16. out ao: bf16 [B*S][1024].
__global__ __launch_bounds__(256) void fattn(const u16* __restrict__ qp,
                                             const u16* __restrict__ kp,
                                             const u16* __restrict__ vt,
                                             u16* __restrict__ ao) {
  __shared__ u16 P[4][32 * 72];             // per-wave P tile [q][key], stride 72
  __shared__ float OM[2][2][4][4][64];      // k-half-1 partial o: [qt][mi][ni][r][lane]
  __shared__ float MM[2][2][64], LL[2][2][64];  // k-half-1 m,l: [qt][mi][lane]

  const int lane = threadIdx.x & 63;
  const int w = threadIdx.x >> 6;
  const int qt = w >> 1;                    // q-tile within block
  const int kh = w & 1;                     // k-half
  const int bh = blockIdx.y;
  const int b = bh >> 4, h = bh & 15;
  const int q0 = blockIdx.x * 64 + qt * 32;
  const u16* qb = qp + (size_t)bh * (2048 * 64);
  const u16* kb = kp + (size_t)bh * (2048 * 64);
  const u16* vb = vt + (size_t)bh * (64 * 2048);
  u16* Pw = &P[w][0];
  const int l15 = lane & 15, l4 = lane >> 4;
  const float KSC = 0.18033688011112042f;   // log2(e) / sqrt(dk)
  const float THR = 8.0f;                   // defer-max threshold (T13)

  // Q fragments (persistent): B-operand, lane l15 = q col, l4*8 = k
  s16x8 qa[2][2];
#pragma unroll
  for (int mi = 0; mi < 2; ++mi)
#pragma unroll
    for (int ks = 0; ks < 2; ++ks)
      qa[mi][ks] = ld_g16(qb + (size_t)(q0 + mi * 16 + l15) * 64 + ks * 32 + l4 * 8);

  f32x4 o[2][4];                            // O[q=l4*4+r + 16mi][d=ni*16+l15]
  float mrun[2], lrun[2];                   // per-lane softmax state for q = mi*16+l15
#pragma unroll
  for (int mi = 0; mi < 2; ++mi) {
#pragma unroll
    for (int ni = 0; ni < 4; ++ni) o[mi][ni] = {0.f, 0.f, 0.f, 0.f};
    mrun[mi] = -1e30f; lrun[mi] = 0.f;
  }

  const int kbeg = kh << 10, kend = kbeg + 1024;
  for (int k0 = kbeg; k0 < kend; k0 += 64) {
    // ---- QK^T (swapped): sc[mi][nk] = D[key][q], key = nk*16 + l4*4 + r, q = mi*16+l15
    f32x4 sc[2][4];
#pragma unroll
    for (int mi = 0; mi < 2; ++mi)
#pragma unroll
      for (int nk = 0; nk < 4; ++nk) sc[mi][nk] = {0.f, 0.f, 0.f, 0.f};
#pragma unroll
    for (int ks = 0; ks < 2; ++ks) {
      s16x8 kf[4];
#pragma unroll
      for (int nk = 0; nk < 4; ++nk)
        kf[nk] = ld_g16(kb + (size_t)(k0 + nk * 16 + l15) * 64 + ks * 32 + l4 * 8);
      __builtin_amdgcn_s_setprio(1);
#pragma unroll
      for (int mi = 0; mi < 2; ++mi)
#pragma unroll
        for (int nk = 0; nk < 4; ++nk)
          sc[mi][nk] = mfma16(kf[nk], qa[mi][ks], sc[mi][nk]);
      __builtin_amdgcn_s_setprio(0);
    }

    // ---- per-q max: in-lane over 16, then xor 16/32 (over l4 groups)
    float smax[2];
#pragma unroll
    for (int mi = 0; mi < 2; ++mi) {
      float a = fmaxf(fmaxf(sc[mi][0][0], sc[mi][0][1]), fmaxf(sc[mi][0][2], sc[mi][0][3]));
      float c = fmaxf(fmaxf(sc[mi][1][0], sc[mi][1][1]), fmaxf(sc[mi][1][2], sc[mi][1][3]));
      float d = fmaxf(fmaxf(sc[mi][2][0], sc[mi][2][1]), fmaxf(sc[mi][2][2], sc[mi][2][3]));
      float e = fmaxf(fmaxf(sc[mi][3][0], sc[mi][3][1]), fmaxf(sc[mi][3][2], sc[mi][3][3]));
      float m = fmaxf(fmaxf(a, c), fmaxf(d, e));
      m = fmaxf(m, __shfl_xor(m, 16));
      m = fmaxf(m, __shfl_xor(m, 32));
      smax[mi] = m * KSC;
    }

    // ---- defer-max: rescale only if some q grew past mrun + THR
    if (__any((smax[0] > mrun[0] + THR) | (smax[1] > mrun[1] + THR))) {
      float alpha[2];
#pragma unroll
      for (int mi = 0; mi < 2; ++mi) {
        float mn = fmaxf(mrun[mi], smax[mi]);
        alpha[mi] = EXP2F(mrun[mi] - mn);
        mrun[mi] = mn;
        lrun[mi] *= alpha[mi];
      }
#pragma unroll
      for (int mi = 0; mi < 2; ++mi) {
#pragma unroll
        for (int r = 0; r < 4; ++r) {
          float ar = __shfl(alpha[mi], l4 * 4 + r);  // q-row layout broadcast
#pragma unroll
          for (int ni = 0; ni < 4; ++ni) o[mi][ni][r] *= ar;
        }
      }
    }

    // ---- P = exp2(sc*KSC - m): lane-local; pack 4 keys -> one b64 LDS store
    float ps[2] = {0.f, 0.f};
#pragma unroll
    for (int mi = 0; mi < 2; ++mi)
#pragma unroll
      for (int nk = 0; nk < 4; ++nk) {
        float p0 = EXP2F(fmaf(sc[mi][nk][0], KSC, -mrun[mi]));
        float p1 = EXP2F(fmaf(sc[mi][nk][1], KSC, -mrun[mi]));
        float p2 = EXP2F(fmaf(sc[mi][nk][2], KSC, -mrun[mi]));
        float p3 = EXP2F(fmaf(sc[mi][nk][3], KSC, -mrun[mi]));
        ps[mi] += (p0 + p1) + (p2 + p3);
        u16x4 pk = {f2b(p0), f2b(p1), f2b(p2), f2b(p3)};
        *(u16x4*)&Pw[(mi * 16 + l15) * 72 + nk * 16 + l4 * 4] = pk;
      }
#pragma unroll
    for (int mi = 0; mi < 2; ++mi) {
      float s = ps[mi];
      s += __shfl_xor(s, 16);
      s += __shfl_xor(s, 32);
      lrun[mi] += s;
    }

    asm volatile("" ::: "memory");
    // ---- PV: o += P @ vT  (A = P from LDS b128, B = vT rows from global/L2)
#pragma unroll
    for (int ks = 0; ks < 2; ++ks) {
      s16x8 pa[2];
      pa[0] = *(const s16x8*)&Pw[(0 * 16 + l15) * 72 + ks * 32 + l4 * 8];
      pa[1] = *(const s16x8*)&Pw[(1 * 16 + l15) * 72 + ks * 32 + l4 * 8];
#pragma unroll
      for (int ni = 0; ni < 4; ++ni) {
        s16x8 vf = ld_g16(vb + (size_t)(ni * 16 + l15) * 2048 + k0 + ks * 32 + l4 * 8);
        __builtin_amdgcn_s_setprio(1);
        o[0][ni] = mfma16(pa[0], vf, o[0][ni]);
        o[1][ni] = mfma16(pa[1], vf, o[1][ni]);
        __builtin_amdgcn_s_setprio(0);
      }
    }
    asm volatile("" ::: "memory");
  }

  // ---- merge the two k-halves (per q-tile) via LDS
  if (kh == 1) {
#pragma unroll
    for (int mi = 0; mi < 2; ++mi) {
      MM[qt][mi][lane] = mrun[mi];
      LL[qt][mi][lane] = lrun[mi];
#pragma unroll
      for (int ni = 0; ni < 4; ++ni)
#pragma unroll
        for (int r = 0; r < 4; ++r) OM[qt][mi][ni][r][lane] = o[mi][ni][r];
    }
  }
  __syncthreads();
  if (kh == 1) return;

  float a0[2], a1[2], lm[2];
#pragma unroll
  for (int mi = 0; mi < 2; ++mi) {
    float m1 = MM[qt][mi][lane], l1 = LL[qt][mi][lane];
    float mn = fmaxf(mrun[mi], m1);
    a0[mi] = EXP2F(mrun[mi] - mn);
    a1[mi] = EXP2F(m1 - mn);
    lm[mi] = lrun[mi] * a0[mi] + l1 * a1[mi];
  }
#pragma unroll
  for (int mi = 0; mi < 2; ++mi)
#pragma unroll
    for (int r = 0; r < 4; ++r) {
      float a0r = __shfl(a0[mi], l4 * 4 + r);
      float a1r = __shfl(a1[mi], l4 * 4 + r);
      float lr  = __shfl(lm[mi], l4 * 4 + r);
      float inv = 1.0f / lr;
#pragma unroll
      for (int ni = 0; ni < 4; ++ni) {
        float val = (o[mi][ni][r] * a0r + OM[qt][mi][ni][r][lane] * a1r) * inv;
        int row = b * 2048 + q0 + mi * 16 + l4 * 4 + r;
        int col = h * 64 + ni * 16 + l15;
        ao[(size_t)row * 1024 + col] = f2b(val);
      }
    }
}

// ---------------------------------------------------------------- host
extern "C" void kernel_launch(void* const* d_in, const int* in_sizes, int n_in,
                              void* d_out, int out_size, void* d_ws, size_t ws_size,
                              hipStream_t stream) {
  const float* Q  = (const float*)d_in[0];
  const float* K  = (const float*)d_in[1];
  const float* V  = (const float*)d_in[2];
  const float* Wq = (const float*)d_in[3];
  const float* bq = (const float*)d_in[4];
  const float* Wk = (const float*)d_in[5];
  const float* bk = (const float*)d_in[6];
  const float* Wv = (const float*)d_in[7];
  const float* bv = (const float*)d_in[8];
  const float* Wo = (const float*)d_in[9];
  const float* bo = (const float*)d_in[10];
  float* out = (float*)d_out;

  const size_t NI = (size_t)4096 * 1024;
  const size_t NW = (size_t)1024 * 1024;
  u16* XB  = (u16*)d_ws;
  u16* WB  = XB + 3 * NI;
  u16* QKV = WB + 4 * NW;
  u16* VT  = QKV + 3 * NI;
  u16* AO  = VT + NI;

  cvt_f32_bf16<<<dim3((int)(NI / 4 / 256)), 256, 0, stream>>>(Q, XB, (int)(NI / 4));
  cvt_f32_bf16<<<dim3((int)(NI / 4 / 256)), 256, 0, stream>>>(K, XB + NI, (int)(NI / 4));
  cvt_f32_bf16<<<dim3((int)(NI / 4 / 256)), 256, 0, stream>>>(V, XB + 2 * NI, (int)(NI / 4));
  cvt_f32_bf16<<<dim3((int)(NW / 4 / 256)), 256, 0, stream>>>(Wq, WB, (int)(NW / 4));
  cvt_f32_bf16<<<dim3((int)(NW / 4 / 256)), 256, 0, stream>>>(Wk, WB + NW, (int)(NW / 4));
  cvt_f32_bf16<<<dim3((int)(NW / 4 / 256)), 256, 0, stream>>>(Wv, WB + 2 * NW, (int)(NW / 4));
  cvt_f32_bf16<<<dim3((int)(NW / 4 / 256)), 256, 0, stream>>>(Wo, WB + 3 * NW, (int)(NW / 4));

  gemm_bt<0><<<dim3(8, 32, 3), 256, 0, stream>>>(XB, WB, bq, bk, bv, QKV, nullptr);
  transpose64<<<dim3(32, 32), 256, 0, stream>>>(QKV + 2 * NI, VT);
  fattn<<<dim3(32, 32), 256, 0, stream>>>(QKV, QKV + NI, VT, AO);
  gemm_bt<1><<<dim3(8, 32, 1), 256, 0, stream>>>(AO, WB + 3 * NW, bo, nullptr, nullptr,
                                                 nullptr, out);
}

// Round 3
// 150.960 us; speedup vs baseline: 1.6852x; 1.5599x over previous
//
#include <hip/hip_runtime.h>
#include <stdint.h>

// MultiHeadAttention fused pipeline for MI355X (gfx950).
// B=2, S=2048, D=1024, H=16, dk=64. fp32 in/out, bf16 MFMA compute.

#define AS1 __attribute__((address_space(1)))
#define AS3 __attribute__((address_space(3)))

typedef unsigned short u16;
typedef short s16x8 __attribute__((ext_vector_type(8)));   // 8 bf16 (4 VGPRs) MFMA frag
typedef float f32x4 __attribute__((ext_vector_type(4)));   // MFMA accumulator
typedef u16   u16x4 __attribute__((ext_vector_type(4)));

#if defined(__has_builtin)
#if __has_builtin(__builtin_amdgcn_exp2f)
#define EXP2F(x) __builtin_amdgcn_exp2f(x)
#else
#define EXP2F(x) exp2f(x)
#endif
#else
#define EXP2F(x) exp2f(x)
#endif

__device__ __forceinline__ u16 f2b(float f) {  // fp32 -> bf16 RNE
  union { float f; uint32_t u; } v;
  v.f = f;
  uint32_t r = (v.u + 0x7fffu + ((v.u >> 16) & 1u)) >> 16;
  return (u16)r;
}

__device__ __forceinline__ f32x4 mfma16(s16x8 a, s16x8 b, f32x4 c) {
  return __builtin_amdgcn_mfma_f32_16x16x32_bf16(a, b, c, 0, 0, 0);
}

__device__ __forceinline__ s16x8 ld_g16(const u16* p) {
  return *reinterpret_cast<const s16x8*>(p);
}

// async global->LDS, 16B per lane. LDS dest must be WAVE-UNIFORM base; HW adds lane*16.
// Global SOURCE is per-lane -> swizzled layouts via pre-swizzled source (m173).
__device__ __forceinline__ void stage16(const u16* g, u16* lds_base) {
  __builtin_amdgcn_global_load_lds((const AS1 unsigned int*)g,
                                   (AS3 unsigned int*)lds_base, 16, 0, 0);
}

// ---------------------------------------------------------------- fused fp32 -> bf16 (all 7 tensors)
struct CvtArgs {
  const float* src[7];
  u16* dst[7];
  int cum[8];   // cumulative block ranges
};

__global__ __launch_bounds__(256) void cvt_all(CvtArgs a) {
  const int bx = blockIdx.x;
  int seg = 0;
#pragma unroll
  for (int i = 1; i < 7; ++i) seg += (bx >= a.cum[i]) ? 1 : 0;
  const int off = (bx - a.cum[seg]) * 256 + threadIdx.x;
  float4 f = reinterpret_cast<const float4*>(a.src[seg])[off];
  union { u16 u[4]; uint64_t q; } o;
  o.u[0] = f2b(f.x); o.u[1] = f2b(f.y); o.u[2] = f2b(f.z); o.u[3] = f2b(f.w);
  reinterpret_cast<uint64_t*>(a.dst[seg])[off] = o.q;
}

// ---------------------------------------------------------------- GEMM  C = A @ W^T + bias
// MODE 0: z in {0,1,2} selects q,k,v. z<2 -> [B,H,S,dk] bf16; z==2 -> VT [B,H,dk,S] bf16.
// MODE 1: out fp32 [4096][1024] (final projection).
template <int MODE>
__global__ __launch_bounds__(256) void gemm_bt(const u16* __restrict__ Abase,
                                               const u16* __restrict__ Wbase,
                                               const float* __restrict__ bias0,
                                               const float* __restrict__ bias1,
                                               const float* __restrict__ bias2,
                                               u16* __restrict__ outb,
                                               u16* __restrict__ vtout,
                                               float* __restrict__ outf) {
  __shared__ u16 As[128 * 32];
  __shared__ u16 Bs[128 * 32];
  const int tid = threadIdx.x;
  const int lane = tid & 63;
  const int w = tid >> 6;
  const int wr = w >> 1, wc = w & 1;       // 2x2 wave grid, each wave 64x64
  const int m0 = blockIdx.y * 128;
  const int n0 = blockIdx.x * 128;
  const int z = (MODE == 0) ? blockIdx.z : 0;

  const u16* A = Abase + (size_t)z * (4096u * 1024u);
  const u16* W = Wbase + (size_t)z * (1024u * 1024u);
  const float* bias = (MODE == 0) ? (z == 0 ? bias0 : (z == 1 ? bias1 : bias2)) : bias0;
  u16* ob = (MODE == 0) ? (outb + (size_t)z * (4096u * 1024u)) : nullptr;

  const int l15 = lane & 15, l4 = lane >> 4;
  const int srow = lane >> 2;
  const int scol = (lane & 3) * 8;
  const int i0 = w * 2, i1 = w * 2 + 1;

  f32x4 acc[4][4];
#pragma unroll
  for (int i = 0; i < 4; ++i)
#pragma unroll
    for (int j = 0; j < 4; ++j) acc[i][j] = {0.f, 0.f, 0.f, 0.f};

  for (int kt = 0; kt < 1024; kt += 32) {
    __syncthreads();
    stage16(A + (size_t)(m0 + i0 * 16 + srow) * 1024 + kt + scol, &As[i0 * 512]);
    stage16(A + (size_t)(m0 + i1 * 16 + srow) * 1024 + kt + scol, &As[i1 * 512]);
    stage16(W + (size_t)(n0 + i0 * 16 + srow) * 1024 + kt + scol, &Bs[i0 * 512]);
    stage16(W + (size_t)(n0 + i1 * 16 + srow) * 1024 + kt + scol, &Bs[i1 * 512]);
    __syncthreads();

    s16x8 af[4], bf[4];
#pragma unroll
    for (int mi = 0; mi < 4; ++mi)
      af[mi] = *(const s16x8*)&As[(wr * 64 + mi * 16 + l15) * 32 + l4 * 8];
#pragma unroll
    for (int ni = 0; ni < 4; ++ni)
      bf[ni] = *(const s16x8*)&Bs[(wc * 64 + ni * 16 + l15) * 32 + l4 * 8];
    __builtin_amdgcn_s_setprio(1);
#pragma unroll
    for (int mi = 0; mi < 4; ++mi)
#pragma unroll
      for (int ni = 0; ni < 4; ++ni)
        acc[mi][ni] = mfma16(af[mi], bf[ni], acc[mi][ni]);
    __builtin_amdgcn_s_setprio(0);
  }

#pragma unroll
  for (int ni = 0; ni < 4; ++ni) {
    const int col = n0 + wc * 64 + ni * 16 + l15;
    const float bv = bias[col];
#pragma unroll
    for (int mi = 0; mi < 4; ++mi) {
      const int row0 = m0 + wr * 64 + mi * 16 + l4 * 4;
      if (MODE == 0 && z == 2) {
        // V projection -> VT [B,H,dk,S]: rows r are contiguous in s -> packed store
        const int b = row0 >> 11, s0 = row0 & 2047;
        const int h = col >> 6, d = col & 63;
        u16x4 pk = {f2b(acc[mi][ni][0] + bv), f2b(acc[mi][ni][1] + bv),
                    f2b(acc[mi][ni][2] + bv), f2b(acc[mi][ni][3] + bv)};
        *(u16x4*)&vtout[((size_t)(b * 16 + h) * 64 + d) * 2048 + s0] = pk;
      } else {
#pragma unroll
        for (int r = 0; r < 4; ++r) {
          const float val = acc[mi][ni][r] + bv;
          const int row = row0 + r;
          if (MODE == 0) {
            const int b = row >> 11, s = row & 2047;
            const int h = col >> 6, d = col & 63;
            ob[((size_t)(b * 16 + h) * 2048 + s) * 64 + d] = f2b(val);
          } else {
            outf[(size_t)row * 1024 + col] = f2b(val), outf[(size_t)row * 1024 + col] = val;
          }
        }
      }
    }
  }
}

// ---------------------------------------------------------------- flash attention
// 8 waves x 32 q-rows = 256 q/block. KVBLK=64, K/V double-buffered in LDS
// (XOR-swizzled via pre-swizzled global source), swapped QK^T softmax, P via LDS.
// q,k: [B,H,S,dk] bf16. vT: [B,H,dk,S] bf16. out ao: bf16 [B*S][1024].
__global__ __launch_bounds__(512) void fattn(const u16* __restrict__ qp,
                                             const u16* __restrict__ kp,
                                             const u16* __restrict__ vt,
                                             u16* __restrict__ ao) {
  __shared__ u16 Kt[2][4096];               // 64 keys x 64 dk, chunk-swizzled
  __shared__ u16 Vt[2][4096];               // 64 d    x 64 keys, chunk-swizzled
  __shared__ u16 P[8][32 * 72];             // per-wave P [q][key], stride 72

  const int lane = threadIdx.x & 63;
  const int w = threadIdx.x >> 6;
  const int bh = blockIdx.y;
  const int b = bh >> 4, h = bh & 15;
  const int q0 = blockIdx.x * 256 + w * 32;
  const u16* qb = qp + (size_t)bh * (2048 * 64);
  const u16* kb = kp + (size_t)bh * (2048 * 64);
  const u16* vb = vt + (size_t)bh * (64 * 2048);
  u16* Pw = P[w];
  const int l15 = lane & 15, l4 = lane >> 4;
  const float KSC = 0.18033688011112042f;   // log2(e) / sqrt(dk)
  const float THR = 8.0f;                   // defer-max threshold (T13)

  // staging geometry: wave w stages storage chunks [w*64, w*64+64) of each 8KB tile.
  // storage chunk s -> row = s>>3, storage col = s&7, logical col = (s&7) ^ (row&7).
  const int srow = (w << 3) + (lane >> 3);
  const int lcol8 = (((lane & 7) ^ (srow & 7)) << 3);   // logical col in elements

  // Q fragments (persistent): B-operand, lane l15 = q col, l4*8 = k offset
  s16x8 qa[2][2];
#pragma unroll
  for (int mi = 0; mi < 2; ++mi)
#pragma unroll
    for (int ks = 0; ks < 2; ++ks)
      qa[mi][ks] = ld_g16(qb + (size_t)(q0 + mi * 16 + l15) * 64 + ks * 32 + l4 * 8);

  f32x4 o[2][4];
  float mrun[2], lrun[2];
#pragma unroll
  for (int mi = 0; mi < 2; ++mi) {
#pragma unroll
    for (int ni = 0; ni < 4; ++ni) o[mi][ni] = {0.f, 0.f, 0.f, 0.f};
    mrun[mi] = -1e30f; lrun[mi] = 0.f;
  }

  // prologue: stage tile 0
  stage16(kb + (size_t)srow * 64 + lcol8, &Kt[0][w * 512]);
  stage16(vb + (size_t)srow * 2048 + lcol8, &Vt[0][w * 512]);
  __syncthreads();

  for (int t = 0; t < 32; ++t) {
    const int cur = t & 1;
    if (t + 1 < 32) {                       // issue next tile early; latency hides under compute
      const int kk = (t + 1) << 6;
      stage16(kb + (size_t)(kk + srow) * 64 + lcol8, &Kt[cur ^ 1][w * 512]);
      stage16(vb + (size_t)srow * 2048 + kk + lcol8, &Vt[cur ^ 1][w * 512]);
    }

    // ---- QK^T (swapped): sc[mi][nk] = D[key][q], key = nk*16+l4*4+r, q = mi*16+l15
    s16x8 kf[2][4];
#pragma unroll
    for (int ks = 0; ks < 2; ++ks)
#pragma unroll
      for (int nk = 0; nk < 4; ++nk) {
        const int row = nk * 16 + l15;
        const int sc_ = (((ks << 2) | l4) ^ (l15 & 7)) << 3;
        kf[ks][nk] = *(const s16x8*)&Kt[cur][row * 64 + sc_];
      }
    f32x4 sc[2][4];
#pragma unroll
    for (int mi = 0; mi < 2; ++mi)
#pragma unroll
      for (int nk = 0; nk < 4; ++nk) sc[mi][nk] = {0.f, 0.f, 0.f, 0.f};
    __builtin_amdgcn_s_setprio(1);
#pragma unroll
    for (int ks = 0; ks < 2; ++ks)
#pragma unroll
      for (int mi = 0; mi < 2; ++mi)
#pragma unroll
        for (int nk = 0; nk < 4; ++nk)
          sc[mi][nk] = mfma16(kf[ks][nk], qa[mi][ks], sc[mi][nk]);
    __builtin_amdgcn_s_setprio(0);

    // ---- per-q max: in-lane over 16 keys, then xor 16/32 across l4 groups
    float smax[2];
#pragma unroll
    for (int mi = 0; mi < 2; ++mi) {
      float a = fmaxf(fmaxf(sc[mi][0][0], sc[mi][0][1]), fmaxf(sc[mi][0][2], sc[mi][0][3]));
      float c = fmaxf(fmaxf(sc[mi][1][0], sc[mi][1][1]), fmaxf(sc[mi][1][2], sc[mi][1][3]));
      float d = fmaxf(fmaxf(sc[mi][2][0], sc[mi][2][1]), fmaxf(sc[mi][2][2], sc[mi][2][3]));
      float e = fmaxf(fmaxf(sc[mi][3][0], sc[mi][3][1]), fmaxf(sc[mi][3][2], sc[mi][3][3]));
      float m = fmaxf(fmaxf(a, c), fmaxf(d, e));
      m = fmaxf(m, __shfl_xor(m, 16));
      m = fmaxf(m, __shfl_xor(m, 32));
      smax[mi] = m * KSC;
    }

    // ---- defer-max rescale (T13)
    if (__any((smax[0] > mrun[0] + THR) | (smax[1] > mrun[1] + THR))) {
      float alpha[2];
#pragma unroll
      for (int mi = 0; mi < 2; ++mi) {
        float mn = fmaxf(mrun[mi], smax[mi]);
        alpha[mi] = EXP2F(mrun[mi] - mn);
        mrun[mi] = mn;
        lrun[mi] *= alpha[mi];
      }
#pragma unroll
      for (int mi = 0; mi < 2; ++mi)
#pragma unroll
        for (int r = 0; r < 4; ++r) {
          float ar = __shfl(alpha[mi], l4 * 4 + r);
#pragma unroll
          for (int ni = 0; ni < 4; ++ni) o[mi][ni][r] *= ar;
        }
    }

    // ---- P = exp2(sc*KSC - m): packed b64 stores to per-wave LDS
    float ps[2] = {0.f, 0.f};
#pragma unroll
    for (int mi = 0; mi < 2; ++mi)
#pragma unroll
      for (int nk = 0; nk < 4; ++nk) {
        float p0 = EXP2F(fmaf(sc[mi][nk][0], KSC, -mrun[mi]));
        float p1 = EXP2F(fmaf(sc[mi][nk][1], KSC, -mrun[mi]));
        float p2 = EXP2F(fmaf(sc[mi][nk][2], KSC, -mrun[mi]));
        float p3 = EXP2F(fmaf(sc[mi][nk][3], KSC, -mrun[mi]));
        ps[mi] += (p0 + p1) + (p2 + p3);
        u16x4 pk = {f2b(p0), f2b(p1), f2b(p2), f2b(p3)};
        *(u16x4*)&Pw[(mi * 16 + l15) * 72 + nk * 16 + l4 * 4] = pk;
      }
#pragma unroll
    for (int mi = 0; mi < 2; ++mi) {
      float s = ps[mi];
      s += __shfl_xor(s, 16);
      s += __shfl_xor(s, 32);
      lrun[mi] += s;
    }

    // ---- PV: o += P @ vT (A = P from LDS, B = V tile from LDS; within-wave DS in-order)
#pragma unroll
    for (int ks = 0; ks < 2; ++ks) {
      s16x8 pa[2];
      pa[0] = *(const s16x8*)&Pw[(0 * 16 + l15) * 72 + ks * 32 + l4 * 8];
      pa[1] = *(const s16x8*)&Pw[(1 * 16 + l15) * 72 + ks * 32 + l4 * 8];
      s16x8 vf[4];
#pragma unroll
      for (int ni = 0; ni < 4; ++ni) {
        const int row = ni * 16 + l15;
        const int sc_ = (((ks << 2) | l4) ^ (l15 & 7)) << 3;
        vf[ni] = *(const s16x8*)&Vt[cur][row * 64 + sc_];
      }
      __builtin_amdgcn_s_setprio(1);
#pragma unroll
      for (int ni = 0; ni < 4; ++ni) {
        o[0][ni] = mfma16(pa[0], vf[ni], o[0][ni]);
        o[1][ni] = mfma16(pa[1], vf[ni], o[1][ni]);
      }
      __builtin_amdgcn_s_setprio(0);
    }

    __syncthreads();   // all reads of buf `cur` done; next-tile stage (vmcnt) drained
  }

  // ---- epilogue: normalize and store bf16 [B*S][1024]
#pragma unroll
  for (int mi = 0; mi < 2; ++mi)
#pragma unroll
    for (int r = 0; r < 4; ++r) {
      float lr = __shfl(lrun[mi], l4 * 4 + r);
      float inv = 1.0f / lr;
      int row = b * 2048 + q0 + mi * 16 + l4 * 4 + r;
#pragma unroll
      for (int ni = 0; ni < 4; ++ni)
        ao[(size_t)row * 1024 + h * 64 + ni * 16 + l15] = f2b(o[mi][ni][r] * inv);
    }
}

// ---------------------------------------------------------------- host
extern "C" void kernel_launch(void* const* d_in, const int* in_sizes, int n_in,
                              void* d_out, int out_size, void* d_ws, size_t ws_size,
                              hipStream_t stream) {
  const float* Q  = (const float*)d_in[0];
  const float* K  = (const float*)d_in[1];
  const float* V  = (const float*)d_in[2];
  const float* Wq = (const float*)d_in[3];
  const float* bq = (const float*)d_in[4];
  const float* Wk = (const float*)d_in[5];
  const float* bk = (const float*)d_in[6];
  const float* Wv = (const float*)d_in[7];
  const float* bv = (const float*)d_in[8];
  const float* Wo = (const float*)d_in[9];
  const float* bo = (const float*)d_in[10];
  float* out = (float*)d_out;

  const size_t NI = (size_t)4096 * 1024;
  const size_t NW = (size_t)1024 * 1024;
  u16* XB  = (u16*)d_ws;          // Qb,Kb,Vb bf16 (3*NI)
  u16* WB  = XB + 3 * NI;         // Wq,Wk,Wv,Wo bf16 (4*NW)
  u16* QKV = WB + 4 * NW;         // q,k [B,H,S,dk] bf16 (slot 2 unused)
  u16* VT  = QKV + 3 * NI;        // vT [B,H,dk,S] bf16
  u16* AO  = VT + NI;             // attention output bf16 [B*S][D]

  CvtArgs ca;
  ca.src[0] = Q;  ca.dst[0] = XB;
  ca.src[1] = K;  ca.dst[1] = XB + NI;
  ca.src[2] = V;  ca.dst[2] = XB + 2 * NI;
  ca.src[3] = Wq; ca.dst[3] = WB;
  ca.src[4] = Wk; ca.dst[4] = WB + NW;
  ca.src[5] = Wv; ca.dst[5] = WB + 2 * NW;
  ca.src[6] = Wo; ca.dst[6] = WB + 3 * NW;
  ca.cum[0] = 0;     ca.cum[1] = 4096;  ca.cum[2] = 8192;  ca.cum[3] = 12288;
  ca.cum[4] = 13312; ca.cum[5] = 14336; ca.cum[6] = 15360; ca.cum[7] = 16384;
  cvt_all<<<dim3(16384), 256, 0, stream>>>(ca);

  // q,k,v projections (z = 0,1,2); z==2 writes VT directly
  gemm_bt<0><<<dim3(8, 32, 3), 256, 0, stream>>>(XB, WB, bq, bk, bv, QKV, VT, nullptr);
  // attention
  fattn<<<dim3(8, 32), 512, 0, stream>>>(QKV, QKV + NI, VT, AO);
  // output projection
  gemm_bt<1><<<dim3(8, 32, 1), 256, 0, stream>>>(AO, WB + 3 * NW, bo, nullptr, nullptr,
                                                 nullptr, nullptr, out);
}

// Round 4
// 149.406 us; speedup vs baseline: 1.7028x; 1.0104x over previous
//
#include <hip/hip_runtime.h>
#include <stdint.h>

// MultiHeadAttention fused pipeline for MI355X (gfx950).
// B=2, S=2048, D=1024, H=16, dk=64. fp32 in/out, bf16 MFMA compute.

#define AS1 __attribute__((address_space(1)))
#define AS3 __attribute__((address_space(3)))

typedef unsigned short u16;
typedef short s16x8 __attribute__((ext_vector_type(8)));   // 8 bf16 (4 VGPRs) MFMA frag
typedef float f32x4 __attribute__((ext_vector_type(4)));   // MFMA accumulator
typedef u16   u16x4 __attribute__((ext_vector_type(4)));

#if defined(__has_builtin)
#if __has_builtin(__builtin_amdgcn_exp2f)
#define EXP2F(x) __builtin_amdgcn_exp2f(x)
#else
#define EXP2F(x) exp2f(x)
#endif
#else
#define EXP2F(x) exp2f(x)
#endif

__device__ __forceinline__ u16 f2b(float f) {  // fp32 -> bf16 RNE
  union { float f; uint32_t u; } v;
  v.f = f;
  uint32_t r = (v.u + 0x7fffu + ((v.u >> 16) & 1u)) >> 16;
  return (u16)r;
}

// packed fp32x2 -> bf16x2 (1 VALU op; no builtin on gfx950 -> inline asm, T12)
__device__ __forceinline__ uint32_t cvtpk(float lo, float hi) {
  uint32_t r;
  asm("v_cvt_pk_bf16_f32 %0, %1, %2" : "=v"(r) : "v"(lo), "v"(hi));
  return r;
}

__device__ __forceinline__ f32x4 mfma16(s16x8 a, s16x8 b, f32x4 c) {
  return __builtin_amdgcn_mfma_f32_16x16x32_bf16(a, b, c, 0, 0, 0);
}

__device__ __forceinline__ s16x8 ld_g16(const u16* p) {
  return *reinterpret_cast<const s16x8*>(p);
}

// async global->LDS, 16B per lane. LDS dest must be WAVE-UNIFORM base; HW adds lane*16.
// Global SOURCE is per-lane -> swizzled layouts via pre-swizzled source (m173).
__device__ __forceinline__ void stage16(const u16* g, u16* lds_base) {
  __builtin_amdgcn_global_load_lds((const AS1 unsigned int*)g,
                                   (AS3 unsigned int*)lds_base, 16, 0, 0);
}

// ---------------------------------------------------------------- fused fp32 -> bf16 (all 7 tensors)
struct CvtArgs {
  const float* src[7];
  u16* dst[7];
  int cum[8];   // cumulative block ranges
};

__global__ __launch_bounds__(256) void cvt_all(CvtArgs a) {
  const int bx = blockIdx.x;
  int seg = 0;
#pragma unroll
  for (int i = 1; i < 7; ++i) seg += (bx >= a.cum[i]) ? 1 : 0;
  const int off = (bx - a.cum[seg]) * 256 + threadIdx.x;
  float4 f = reinterpret_cast<const float4*>(a.src[seg])[off];
  union { u16 u[4]; uint64_t q; } o;
  o.u[0] = f2b(f.x); o.u[1] = f2b(f.y); o.u[2] = f2b(f.z); o.u[3] = f2b(f.w);
  reinterpret_cast<uint64_t*>(a.dst[seg])[off] = o.q;
}

// ---------------------------------------------------------------- GEMM  C = A @ W^T + bias
// MODE 0: z in {0,1,2} selects q,k,v. z<2 -> [B,H,S,dk] bf16; z==2 -> VT [B,H,dk,S] bf16.
// MODE 1: out fp32 [4096][1024] (final projection).
template <int MODE>
__global__ __launch_bounds__(256) void gemm_bt(const u16* __restrict__ Abase,
                                               const u16* __restrict__ Wbase,
                                               const float* __restrict__ bias0,
                                               const float* __restrict__ bias1,
                                               const float* __restrict__ bias2,
                                               u16* __restrict__ outb,
                                               u16* __restrict__ vtout,
                                               float* __restrict__ outf) {
  __shared__ u16 As[128 * 32];
  __shared__ u16 Bs[128 * 32];
  const int tid = threadIdx.x;
  const int lane = tid & 63;
  const int w = tid >> 6;
  const int wr = w >> 1, wc = w & 1;       // 2x2 wave grid, each wave 64x64
  const int m0 = blockIdx.y * 128;
  const int n0 = blockIdx.x * 128;
  const int z = (MODE == 0) ? blockIdx.z : 0;

  const u16* A = Abase + (size_t)z * (4096u * 1024u);
  const u16* W = Wbase + (size_t)z * (1024u * 1024u);
  const float* bias = (MODE == 0) ? (z == 0 ? bias0 : (z == 1 ? bias1 : bias2)) : bias0;
  u16* ob = (MODE == 0) ? (outb + (size_t)z * (4096u * 1024u)) : nullptr;

  const int l15 = lane & 15, l4 = lane >> 4;
  const int srow = lane >> 2;
  const int scol = (lane & 3) * 8;
  const int i0 = w * 2, i1 = w * 2 + 1;

  f32x4 acc[4][4];
#pragma unroll
  for (int i = 0; i < 4; ++i)
#pragma unroll
    for (int j = 0; j < 4; ++j) acc[i][j] = {0.f, 0.f, 0.f, 0.f};

  for (int kt = 0; kt < 1024; kt += 32) {
    __syncthreads();
    stage16(A + (size_t)(m0 + i0 * 16 + srow) * 1024 + kt + scol, &As[i0 * 512]);
    stage16(A + (size_t)(m0 + i1 * 16 + srow) * 1024 + kt + scol, &As[i1 * 512]);
    stage16(W + (size_t)(n0 + i0 * 16 + srow) * 1024 + kt + scol, &Bs[i0 * 512]);
    stage16(W + (size_t)(n0 + i1 * 16 + srow) * 1024 + kt + scol, &Bs[i1 * 512]);
    __syncthreads();

    s16x8 af[4], bf[4];
#pragma unroll
    for (int mi = 0; mi < 4; ++mi)
      af[mi] = *(const s16x8*)&As[(wr * 64 + mi * 16 + l15) * 32 + l4 * 8];
#pragma unroll
    for (int ni = 0; ni < 4; ++ni)
      bf[ni] = *(const s16x8*)&Bs[(wc * 64 + ni * 16 + l15) * 32 + l4 * 8];
    __builtin_amdgcn_s_setprio(1);
#pragma unroll
    for (int mi = 0; mi < 4; ++mi)
#pragma unroll
      for (int ni = 0; ni < 4; ++ni)
        acc[mi][ni] = mfma16(af[mi], bf[ni], acc[mi][ni]);
    __builtin_amdgcn_s_setprio(0);
  }

#pragma unroll
  for (int ni = 0; ni < 4; ++ni) {
    const int col = n0 + wc * 64 + ni * 16 + l15;
    const float bv = bias[col];
#pragma unroll
    for (int mi = 0; mi < 4; ++mi) {
      const int row0 = m0 + wr * 64 + mi * 16 + l4 * 4;
      if (MODE == 0 && z == 2) {
        // V projection -> VT [B,H,dk,S]: rows r are contiguous in s -> packed store
        const int b = row0 >> 11, s0 = row0 & 2047;
        const int h = col >> 6, d = col & 63;
        u16x4 pk = {f2b(acc[mi][ni][0] + bv), f2b(acc[mi][ni][1] + bv),
                    f2b(acc[mi][ni][2] + bv), f2b(acc[mi][ni][3] + bv)};
        *(u16x4*)&vtout[((size_t)(b * 16 + h) * 64 + d) * 2048 + s0] = pk;
      } else {
#pragma unroll
        for (int r = 0; r < 4; ++r) {
          const float val = acc[mi][ni][r] + bv;
          const int row = row0 + r;
          if (MODE == 0) {
            const int b = row >> 11, s = row & 2047;
            const int h = col >> 6, d = col & 63;
            ob[((size_t)(b * 16 + h) * 2048 + s) * 64 + d] = f2b(val);
          } else {
            outf[(size_t)row * 1024 + col] = val;
          }
        }
      }
    }
  }
}

// ---------------------------------------------------------------- flash attention
// 4 waves x 32 q-rows = 128 q/block; grid (16,32) = 512 blocks = 2 blocks/CU.
// KVBLK=64, K/V double-buffered in LDS (XOR-swizzled via pre-swizzled source),
// swapped QK^T softmax (lane-local row), P via per-wave LDS, cvt_pk packing.
// q,k: [B,H,S,dk] bf16. vT: [B,H,dk,S] bf16. out ao: bf16 [B*S][1024].
__global__ __launch_bounds__(256) void fattn(const u16* __restrict__ qp,
                                             const u16* __restrict__ kp,
                                             const u16* __restrict__ vt,
                                             u16* __restrict__ ao) {
  __shared__ u16 Kt[2][4096];               // 64 keys x 64 dk, chunk-swizzled
  __shared__ u16 Vt[2][4096];               // 64 d    x 64 keys, chunk-swizzled
  __shared__ u16 P[4][32 * 72];             // per-wave P [q][key], stride 72

  const int lane = threadIdx.x & 63;
  const int w = threadIdx.x >> 6;
  const int bh = blockIdx.y;
  const int b = bh >> 4, h = bh & 15;
  const int q0 = blockIdx.x * 128 + w * 32;
  const u16* qb = qp + (size_t)bh * (2048 * 64);
  const u16* kb = kp + (size_t)bh * (2048 * 64);
  const u16* vb = vt + (size_t)bh * (64 * 2048);
  u16* Pw = P[w];
  const int l15 = lane & 15, l4 = lane >> 4;
  const float KSC = 0.18033688011112042f;   // log2(e) / sqrt(dk)
  const float THR = 8.0f;                   // defer-max threshold (T13)

  // staging geometry: wave w stages storage chunks [w*128, w*128+128) of each 8KB
  // tile as two 64-chunk calls. chunk s -> row s>>3, storage col s&7,
  // logical col = (s&7) ^ (row&7). r1 = r0+8 keeps (row&7) -> same swizzled col.
  const int r0 = (w << 4) + (lane >> 3);
  const int r1 = r0 + 8;
  const int c0 = ((lane & 7) ^ (r0 & 7)) << 3;    // logical col in elements

  // Q fragments (persistent): B-operand, lane l15 = q col, l4*8 = k offset
  s16x8 qa[2][2];
#pragma unroll
  for (int mi = 0; mi < 2; ++mi)
#pragma unroll
    for (int ks = 0; ks < 2; ++ks)
      qa[mi][ks] = ld_g16(qb + (size_t)(q0 + mi * 16 + l15) * 64 + ks * 32 + l4 * 8);

  f32x4 o[2][4];
  float mrun[2], lrun[2];
#pragma unroll
  for (int mi = 0; mi < 2; ++mi) {
#pragma unroll
    for (int ni = 0; ni < 4; ++ni) o[mi][ni] = {0.f, 0.f, 0.f, 0.f};
    mrun[mi] = -1e30f; lrun[mi] = 0.f;
  }

  // prologue: stage tile 0
  stage16(kb + (size_t)r0 * 64 + c0, &Kt[0][w * 1024]);
  stage16(kb + (size_t)r1 * 64 + c0, &Kt[0][w * 1024 + 512]);
  stage16(vb + (size_t)r0 * 2048 + c0, &Vt[0][w * 1024]);
  stage16(vb + (size_t)r1 * 2048 + c0, &Vt[0][w * 1024 + 512]);
  __syncthreads();

  for (int t = 0; t < 32; ++t) {
    const int cur = t & 1;
    if (t + 1 < 32) {                       // issue next tile early; hides under compute
      const int kk = (t + 1) << 6;
      stage16(kb + (size_t)(kk + r0) * 64 + c0, &Kt[cur ^ 1][w * 1024]);
      stage16(kb + (size_t)(kk + r1) * 64 + c0, &Kt[cur ^ 1][w * 1024 + 512]);
      stage16(vb + (size_t)r0 * 2048 + kk + c0, &Vt[cur ^ 1][w * 1024]);
      stage16(vb + (size_t)r1 * 2048 + kk + c0, &Vt[cur ^ 1][w * 1024 + 512]);
    }

    // ---- QK^T (swapped): sc[mi][nk] = D[key][q], key = nk*16+l4*4+r, q = mi*16+l15
    s16x8 kf[2][4];
#pragma unroll
    for (int ks = 0; ks < 2; ++ks)
#pragma unroll
      for (int nk = 0; nk < 4; ++nk) {
        const int row = nk * 16 + l15;
        const int sc_ = (((ks << 2) | l4) ^ (l15 & 7)) << 3;
        kf[ks][nk] = *(const s16x8*)&Kt[cur][row * 64 + sc_];
      }
    f32x4 sc[2][4];
#pragma unroll
    for (int mi = 0; mi < 2; ++mi)
#pragma unroll
      for (int nk = 0; nk < 4; ++nk) sc[mi][nk] = {0.f, 0.f, 0.f, 0.f};
    __builtin_amdgcn_s_setprio(1);
#pragma unroll
    for (int ks = 0; ks < 2; ++ks)
#pragma unroll
      for (int mi = 0; mi < 2; ++mi)
#pragma unroll
        for (int nk = 0; nk < 4; ++nk)
          sc[mi][nk] = mfma16(kf[ks][nk], qa[mi][ks], sc[mi][nk]);
    __builtin_amdgcn_s_setprio(0);

    // ---- per-q max: in-lane over 16 keys, then xor 16/32 across l4 groups
    float smax[2];
#pragma unroll
    for (int mi = 0; mi < 2; ++mi) {
      float a = fmaxf(fmaxf(sc[mi][0][0], sc[mi][0][1]), fmaxf(sc[mi][0][2], sc[mi][0][3]));
      float c = fmaxf(fmaxf(sc[mi][1][0], sc[mi][1][1]), fmaxf(sc[mi][1][2], sc[mi][1][3]));
      float d = fmaxf(fmaxf(sc[mi][2][0], sc[mi][2][1]), fmaxf(sc[mi][2][2], sc[mi][2][3]));
      float e = fmaxf(fmaxf(sc[mi][3][0], sc[mi][3][1]), fmaxf(sc[mi][3][2], sc[mi][3][3]));
      float m = fmaxf(fmaxf(a, c), fmaxf(d, e));
      m = fmaxf(m, __shfl_xor(m, 16));
      m = fmaxf(m, __shfl_xor(m, 32));
      smax[mi] = m * KSC;
    }

    // ---- defer-max rescale (T13)
    if (__any((smax[0] > mrun[0] + THR) | (smax[1] > mrun[1] + THR))) {
      float alpha[2];
#pragma unroll
      for (int mi = 0; mi < 2; ++mi) {
        float mn = fmaxf(mrun[mi], smax[mi]);
        alpha[mi] = EXP2F(mrun[mi] - mn);
        mrun[mi] = mn;
        lrun[mi] *= alpha[mi];
      }
#pragma unroll
      for (int mi = 0; mi < 2; ++mi)
#pragma unroll
        for (int r = 0; r < 4; ++r) {
          float ar = __shfl(alpha[mi], l4 * 4 + r);
#pragma unroll
          for (int ni = 0; ni < 4; ++ni) o[mi][ni][r] *= ar;
        }
    }

    // ---- P = exp2(sc*KSC - m): cvt_pk packing, 8B LDS stores
    float ps[2] = {0.f, 0.f};
#pragma unroll
    for (int mi = 0; mi < 2; ++mi)
#pragma unroll
      for (int nk = 0; nk < 4; ++nk) {
        float p0 = EXP2F(fmaf(sc[mi][nk][0], KSC, -mrun[mi]));
        float p1 = EXP2F(fmaf(sc[mi][nk][1], KSC, -mrun[mi]));
        float p2 = EXP2F(fmaf(sc[mi][nk][2], KSC, -mrun[mi]));
        float p3 = EXP2F(fmaf(sc[mi][nk][3], KSC, -mrun[mi]));
        ps[mi] += (p0 + p1) + (p2 + p3);
        uint2 pk;
        pk.x = cvtpk(p0, p1);
        pk.y = cvtpk(p2, p3);
        *(uint2*)&Pw[(mi * 16 + l15) * 72 + nk * 16 + l4 * 4] = pk;
      }
#pragma unroll
    for (int mi = 0; mi < 2; ++mi) {
      float s = ps[mi];
      s += __shfl_xor(s, 16);
      s += __shfl_xor(s, 32);
      lrun[mi] += s;
    }

    // ---- PV: o += P @ vT (A = P from LDS, B = V tile from LDS; within-wave DS in-order)
#pragma unroll
    for (int ks = 0; ks < 2; ++ks) {
      s16x8 pa[2];
      pa[0] = *(const s16x8*)&Pw[(0 * 16 + l15) * 72 + ks * 32 + l4 * 8];
      pa[1] = *(const s16x8*)&Pw[(1 * 16 + l15) * 72 + ks * 32 + l4 * 8];
      s16x8 vf[4];
#pragma unroll
      for (int ni = 0; ni < 4; ++ni) {
        const int row = ni * 16 + l15;
        const int sc_ = (((ks << 2) | l4) ^ (l15 & 7)) << 3;
        vf[ni] = *(const s16x8*)&Vt[cur][row * 64 + sc_];
      }
      __builtin_amdgcn_s_setprio(1);
#pragma unroll
      for (int ni = 0; ni < 4; ++ni) {
        o[0][ni] = mfma16(pa[0], vf[ni], o[0][ni]);
        o[1][ni] = mfma16(pa[1], vf[ni], o[1][ni]);
      }
      __builtin_amdgcn_s_setprio(0);
    }

    __syncthreads();   // all reads of buf `cur` done; next-tile stage (vmcnt) drained
  }

  // ---- epilogue: normalize and store bf16 [B*S][1024]
#pragma unroll
  for (int mi = 0; mi < 2; ++mi)
#pragma unroll
    for (int r = 0; r < 4; ++r) {
      float lr = __shfl(lrun[mi], l4 * 4 + r);
      float inv = 1.0f / lr;
      int row = b * 2048 + q0 + mi * 16 + l4 * 4 + r;
#pragma unroll
      for (int ni = 0; ni < 4; ++ni)
        ao[(size_t)row * 1024 + h * 64 + ni * 16 + l15] = f2b(o[mi][ni][r] * inv);
    }
}

// ---------------------------------------------------------------- host
extern "C" void kernel_launch(void* const* d_in, const int* in_sizes, int n_in,
                              void* d_out, int out_size, void* d_ws, size_t ws_size,
                              hipStream_t stream) {
  const float* Q  = (const float*)d_in[0];
  const float* K  = (const float*)d_in[1];
  const float* V  = (const float*)d_in[2];
  const float* Wq = (const float*)d_in[3];
  const float* bq = (const float*)d_in[4];
  const float* Wk = (const float*)d_in[5];
  const float* bk = (const float*)d_in[6];
  const float* Wv = (const float*)d_in[7];
  const float* bv = (const float*)d_in[8];
  const float* Wo = (const float*)d_in[9];
  const float* bo = (const float*)d_in[10];
  float* out = (float*)d_out;

  const size_t NI = (size_t)4096 * 1024;
  const size_t NW = (size_t)1024 * 1024;
  u16* XB  = (u16*)d_ws;          // Qb,Kb,Vb bf16 (3*NI)
  u16* WB  = XB + 3 * NI;         // Wq,Wk,Wv,Wo bf16 (4*NW)
  u16* QKV = WB + 4 * NW;         // q,k [B,H,S,dk] bf16 (slot 2 unused)
  u16* VT  = QKV + 3 * NI;        // vT [B,H,dk,S] bf16
  u16* AO  = VT + NI;             // attention output bf16 [B*S][D]

  CvtArgs ca;
  ca.src[0] = Q;  ca.dst[0] = XB;
  ca.src[1] = K;  ca.dst[1] = XB + NI;
  ca.src[2] = V;  ca.dst[2] = XB + 2 * NI;
  ca.src[3] = Wq; ca.dst[3] = WB;
  ca.src[4] = Wk; ca.dst[4] = WB + NW;
  ca.src[5] = Wv; ca.dst[5] = WB + 2 * NW;
  ca.src[6] = Wo; ca.dst[6] = WB + 3 * NW;
  ca.cum[0] = 0;     ca.cum[1] = 4096;  ca.cum[2] = 8192;  ca.cum[3] = 12288;
  ca.cum[4] = 13312; ca.cum[5] = 14336; ca.cum[6] = 15360; ca.cum[7] = 16384;
  cvt_all<<<dim3(16384), 256, 0, stream>>>(ca);

  // q,k,v projections (z = 0,1,2); z==2 writes VT directly
  gemm_bt<0><<<dim3(8, 32, 3), 256, 0, stream>>>(XB, WB, bq, bk, bv, QKV, VT, nullptr);
  // attention
  fattn<<<dim3(16, 32), 256, 0, stream>>>(QKV, QKV + NI, VT, AO);
  // output projection
  gemm_bt<1><<<dim3(8, 32, 1), 256, 0, stream>>>(AO, WB + 3 * NW, bo, nullptr, nullptr,
                                                 nullptr, nullptr, out);
}